// Round 7
// baseline (95.559 us; speedup 1.0000x reference)
//
#include <hip/hip_runtime.h>
#include <hip/hip_bf16.h>
#include <math.h>

// Gaussian upsampling, round 7: ABLATION ROUND.
//   transpose_enc_bf16 -> probe_store -> probe_kloop -> gauss_up_mfma (R5, real)
//   probe_store : epilogue store pattern + PE only (pure write floor)
//   probe_kloop : R5 kernel with global stores replaced by keepalives
//   main        : R5 kernel verbatim (fastest measured, 45.2 us), runs last

typedef short  bf16x8 __attribute__((ext_vector_type(8)));
typedef float  f32x4  __attribute__((ext_vector_type(4)));
typedef int    i32x4  __attribute__((ext_vector_type(4)));
typedef unsigned short u16x8 __attribute__((ext_vector_type(8)));

#define S_FIX 256
#define D_FIX 256
#define BM 32          // t-rows per block
#define BN 64          // d-cols per wave
#define STG 68         // staging stride in floats

static __device__ __forceinline__ unsigned short f2bf(float f) {
    union { float f; unsigned u; } v; v.f = f;
    unsigned r = v.u + 0x7FFFu + ((v.u >> 16) & 1u);   // RNE
    return (unsigned short)(r >> 16);
}

static __device__ __forceinline__ unsigned pack_bf2(float lo, float hi) {
    float2 v; v.x = lo; v.y = hi;
    union { __hip_bfloat162 h; unsigned u; } c;
    c.h = __float22bfloat162_rn(v);
    return c.u;
}

// ---------------- prepass: enc (B,S,D) f32 -> encT (B,D,S) bf16 ----------------
__global__ __launch_bounds__(256) void transpose_enc_bf16(
    const float* __restrict__ enc, unsigned short* __restrict__ encT)
{
    const int g  = blockIdx.x * 256 + threadIdx.x;
    const int d  = g & 255;
    const int sc = (g >> 8) & 31;
    const int b  = g >> 13;
    const int s0 = sc * 8;
    const float* p = enc + ((size_t)b << 16) + (size_t)s0 * D_FIX + d;
    u16x8 v;
    #pragma unroll
    for (int j = 0; j < 8; ++j) v[j] = f2bf(p[(size_t)j * D_FIX]);
    *(u16x8*)(encT + ((size_t)b << 16) + (size_t)d * S_FIX + s0) = v;
}

// ---------------- probe A: store-only (epilogue pattern + PE values) ----------------
__global__ __launch_bounds__(256) void probe_store(float* __restrict__ out, int T)
{
    const int tid  = threadIdx.x;
    const int lane = tid & 63;
    const int wid  = tid >> 6;
    const int l15  = lane & 15;
    const int lg   = lane >> 4;
    const int ntiles = T / BM;
    const int b    = blockIdx.x / ntiles;
    const int t0   = (blockIdx.x % ntiles) * BM;
    const int d0   = wid * BN;

    const float kf  = -logf(10000.0f) / (float)D_FIX;
    const float fr0 = __expf(kf * (float)(d0 + 4 * l15));
    const float fr2 = __expf(kf * (float)(d0 + 4 * l15 + 2));
    float* ob = out + (size_t)b * T * D_FIX + (size_t)t0 * D_FIX + d0 + 4 * l15;

    #pragma unroll
    for (int m = 0; m < 2; ++m) {
        #pragma unroll
        for (int i = 0; i < 4; ++i) {
            const int rr = 4 * i + lg;
            const float t = (float)(t0 + m * 16 + rr);
            float sa, ca2, sb, cb2;
            __sincosf(t * fr0, &sa, &ca2);
            __sincosf(t * fr2, &sb, &cb2);
            f32x4 v; v[0] = sa; v[1] = ca2; v[2] = sb; v[3] = cb2;
            *(f32x4*)(ob + (size_t)(m * 16 + rr) * D_FIX) = v;
        }
    }
}

// ---------------- shared body for probe_kloop / main (R5 structure) ----------------
template <bool DO_STORE>
static __device__ __forceinline__ void gauss_body(
    const float* __restrict__ dur, const float* __restrict__ rng,
    const unsigned short* __restrict__ encT, float* __restrict__ out, int T,
    float* s_c, float* s_nir, float* s_stg)
{
    const int tid  = threadIdx.x;
    const int lane = tid & 63;
    const int wid  = tid >> 6;
    const int l15  = lane & 15;
    const int lg   = lane >> 4;
    const int ntiles = T / BM;
    const int b    = blockIdx.x / ntiles;
    const int t0   = (blockIdx.x % ntiles) * BM;
    const int d0   = wid * BN;

    // ---- per-wave scan (identical-value benign race, no barrier) ----
    {
        f32x4 dv = *(const f32x4*)(dur + b * S_FIX + 4 * lane);
        f32x4 rg = *(const f32x4*)(rng + b * S_FIX + 4 * lane);
        float q0 = dv[0];
        float q1 = q0 + dv[1];
        float q2 = q1 + dv[2];
        float q3 = q2 + dv[3];
        float tot = q3;
        #pragma unroll
        for (int off = 1; off < 64; off <<= 1) {
            float n = __shfl_up(tot, off, 64);
            if (lane >= off) tot += n;
        }
        float excl = __shfl_up(tot, 1, 64);
        if (lane == 0) excl = 0.0f;
        f32x4 c4, n4;
        c4[0] = excl + q0 - 0.5f * dv[0];
        c4[1] = excl + q1 - 0.5f * dv[1];
        c4[2] = excl + q2 - 0.5f * dv[2];
        c4[3] = excl + q3 - 0.5f * dv[3];
        #pragma unroll
        for (int i = 0; i < 4; ++i) n4[i] = -1.0f / (rg[i] * rg[i]);
        *(f32x4*)(s_c   + 4 * lane) = c4;
        *(f32x4*)(s_nir + 4 * lane) = n4;
    }
    asm volatile("s_waitcnt lgkmcnt(0)" ::: "memory");

    // ---- k-loop: prefetched global B, register A, 8 MFMA per step ----
    f32x4 acc[2][4];
    #pragma unroll
    for (int m = 0; m < 2; ++m)
        #pragma unroll
        for (int n = 0; n < 4; ++n) acc[m][n] = (f32x4){0.f, 0.f, 0.f, 0.f};

    float sum0 = 0.0f, sum1 = 0.0f;
    const float tt0 = (float)(t0 + l15);
    const float tt1 = (float)(t0 + 16 + l15);
    const unsigned short* eb =
        encT + ((size_t)b << 16) + (size_t)(d0 + l15) * S_FIX + lg * 8;

    bf16x8 bcur[4];
    #pragma unroll
    for (int n = 0; n < 4; ++n)
        bcur[n] = *(const bf16x8*)(eb + (size_t)n * 16 * S_FIX);

    #pragma unroll 2
    for (int k0 = 0; k0 < S_FIX; k0 += 32) {
        const int kn = (k0 + 32 < S_FIX) ? k0 + 32 : 0;
        bf16x8 bnext[4];
        #pragma unroll
        for (int n = 0; n < 4; ++n)
            bnext[n] = *(const bf16x8*)(eb + (size_t)n * 16 * S_FIX + kn);

        f32x4 cA = *(const f32x4*)(s_c   + k0 + lg * 8);
        f32x4 cB = *(const f32x4*)(s_c   + k0 + lg * 8 + 4);
        f32x4 nA = *(const f32x4*)(s_nir + k0 + lg * 8);
        f32x4 nB = *(const f32x4*)(s_nir + k0 + lg * 8 + 4);

        i32x4 a0i, a1i;
        #pragma unroll
        for (int j2 = 0; j2 < 4; ++j2) {
            const float ca_ = (j2 < 2) ? cA[(2 * j2) & 3]     : cB[(2 * j2) & 3];
            const float cb_ = (j2 < 2) ? cA[(2 * j2 + 1) & 3] : cB[(2 * j2 + 1) & 3];
            const float na_ = (j2 < 2) ? nA[(2 * j2) & 3]     : nB[(2 * j2) & 3];
            const float nb_ = (j2 < 2) ? nA[(2 * j2 + 1) & 3] : nB[(2 * j2 + 1) & 3];
            float e0a = tt0 - ca_, e0b = tt0 - cb_;
            float e1a = tt1 - ca_, e1b = tt1 - cb_;
            unsigned p0 = pack_bf2(__expf(na_ * e0a * e0a), __expf(nb_ * e0b * e0b));
            unsigned p1 = pack_bf2(__expf(na_ * e1a * e1a), __expf(nb_ * e1b * e1b));
            a0i[j2] = (int)p0;
            a1i[j2] = (int)p1;
            sum0 += __uint_as_float(p0 << 16) + __uint_as_float(p0 & 0xFFFF0000u);
            sum1 += __uint_as_float(p1 << 16) + __uint_as_float(p1 & 0xFFFF0000u);
        }
        union { i32x4 i; bf16x8 v; } ua, ub;
        ua.i = a0i; ub.i = a1i;
        #pragma unroll
        for (int n = 0; n < 4; ++n) {
            acc[0][n] = __builtin_amdgcn_mfma_f32_16x16x32_bf16(ua.v, bcur[n], acc[0][n], 0, 0, 0);
            acc[1][n] = __builtin_amdgcn_mfma_f32_16x16x32_bf16(ub.v, bcur[n], acc[1][n], 0, 0, 0);
        }
        #pragma unroll
        for (int n = 0; n < 4; ++n) bcur[n] = bnext[n];
    }

    // ---- w2 ----
    sum0 += __shfl_xor(sum0, 16, 64);
    sum0 += __shfl_xor(sum0, 32, 64);
    sum1 += __shfl_xor(sum1, 16, 64);
    sum1 += __shfl_xor(sum1, 32, 64);
    const float inv0 = 1.0f / (sum0 + 1e-20f);
    const float inv1 = 1.0f / (sum1 + 1e-20f);

    // ---- epilogue: per-wave LDS transpose + PE; store or keepalive ----
    float* stg = s_stg + wid * (16 * STG);
    const float kf  = -logf(10000.0f) / (float)D_FIX;
    const float fr0 = __expf(kf * (float)(d0 + 4 * l15));
    const float fr2 = __expf(kf * (float)(d0 + 4 * l15 + 2));
    float* ob = out + (size_t)b * T * D_FIX + (size_t)t0 * D_FIX + d0;

    #pragma unroll
    for (int m = 0; m < 2; ++m) {
        asm volatile("s_waitcnt lgkmcnt(0)" ::: "memory");
        #pragma unroll
        for (int n = 0; n < 4; ++n)
            #pragma unroll
            for (int r = 0; r < 4; ++r)
                stg[(lg * 4 + r) * STG + n * 16 + l15] = acc[m][n][r];
        asm volatile("s_waitcnt lgkmcnt(0)" ::: "memory");
        const float invm = m ? inv1 : inv0;
        #pragma unroll
        for (int i = 0; i < 4; ++i) {
            const int rr = 4 * i + lg;
            f32x4 v = *(const f32x4*)(stg + rr * STG + 4 * l15);
            const float iv = __shfl(invm, rr, 64);
            const float t  = (float)(t0 + m * 16 + rr);
            float sa, ca2, sb, cb2;
            __sincosf(t * fr0, &sa, &ca2);
            __sincosf(t * fr2, &sb, &cb2);
            v[0] = v[0] * iv + sa;
            v[1] = v[1] * iv + ca2;
            v[2] = v[2] * iv + sb;
            v[3] = v[3] * iv + cb2;
            if (DO_STORE) {
                *(f32x4*)(ob + (size_t)(m * 16 + rr) * D_FIX + 4 * l15) = v;
            } else {
                asm volatile("" :: "v"(v[0]), "v"(v[1]), "v"(v[2]), "v"(v[3]));
            }
        }
    }
}

// ---------------- probe B: full R5 body, stores stubbed ----------------
__global__ __launch_bounds__(256) void probe_kloop(
    const float* __restrict__ dur, const float* __restrict__ rng,
    const unsigned short* __restrict__ encT, float* __restrict__ out, int T)
{
    __shared__ float s_c[S_FIX];
    __shared__ float s_nir[S_FIX];
    __shared__ __align__(16) float s_stg[4 * 16 * STG];
    gauss_body<false>(dur, rng, encT, out, T, s_c, s_nir, s_stg);
}

// ---------------- main: R5 kernel ----------------
__global__ __launch_bounds__(256) void gauss_up_mfma(
    const float* __restrict__ dur, const float* __restrict__ rng,
    const unsigned short* __restrict__ encT, float* __restrict__ out, int T)
{
    __shared__ float s_c[S_FIX];
    __shared__ float s_nir[S_FIX];
    __shared__ __align__(16) float s_stg[4 * 16 * STG];
    gauss_body<true>(dur, rng, encT, out, T, s_c, s_nir, s_stg);
}

// ---------------- fallback (round-1 f32 kernel) ----------------
#define FBM 32
#define BLOCK 256
__global__ __launch_bounds__(BLOCK) void gauss_up_f32(
    const float* __restrict__ enc, const float* __restrict__ dur,
    const float* __restrict__ rng, float* __restrict__ out,
    int T, int D, int ntiles)
{
    __shared__ float s_w[FBM][S_FIX];
    __shared__ float s_c[S_FIX];
    __shared__ float s_ir2[S_FIX];
    __shared__ float s_scan[S_FIX];
    __shared__ float s_part[8][FBM];
    __shared__ float s_winv[FBM];

    const int tid = threadIdx.x;
    const int b   = blockIdx.x / ntiles;
    const int t0  = (blockIdx.x % ntiles) * FBM;

    float dv = dur[b * S_FIX + tid];
    s_scan[tid] = dv;
    __syncthreads();
    #pragma unroll
    for (int off = 1; off < S_FIX; off <<= 1) {
        float cur = s_scan[tid];
        float add = (tid >= off) ? s_scan[tid - off] : 0.0f;
        __syncthreads();
        s_scan[tid] = cur + add;
        __syncthreads();
    }
    {
        float e = s_scan[tid];
        float c = e - 0.5f * dv;
        float r = rng[b * S_FIX + tid];
        s_c[tid] = c; s_ir2[tid] = 1.0f / (r * r);
    }
    __syncthreads();
    {
        float cc = s_c[tid], ir = s_ir2[tid];
        #pragma unroll 4
        for (int tl = 0; tl < FBM; ++tl) {
            float tt = (float)(t0 + tl);
            float df = tt - cc;
            s_w[tl][tid] = __expf(-ir * df * df);
        }
    }
    __syncthreads();
    {
        const int t = tid & 31, ch = tid >> 5;
        float ps = 0.0f;
        #pragma unroll 8
        for (int j = 0; j < 32; ++j) ps += s_w[t][ch * 32 + ((j + t) & 31)];
        s_part[ch][t] = ps;
    }
    __syncthreads();
    if (tid < FBM) {
        float w2 = s_part[0][tid] + s_part[1][tid] + s_part[2][tid] + s_part[3][tid]
                 + s_part[4][tid] + s_part[5][tid] + s_part[6][tid] + s_part[7][tid] + 1e-20f;
        s_winv[tid] = 1.0f / w2;
    }
    __syncthreads();

    const int dq = tid & 63, tg = tid >> 6;
    float4 acc[8];
    #pragma unroll
    for (int i = 0; i < 8; ++i) acc[i] = make_float4(0.f, 0.f, 0.f, 0.f);
    const float* encb = enc + (size_t)b * S_FIX * D + (size_t)dq * 4;
    #pragma unroll 4
    for (int s = 0; s < S_FIX; ++s) {
        float4 ev = *(const float4*)(encb + (size_t)s * D);
        #pragma unroll
        for (int i = 0; i < 8; ++i) {
            float wv = s_w[tg * 8 + i][s];
            acc[i].x = fmaf(wv, ev.x, acc[i].x);
            acc[i].y = fmaf(wv, ev.y, acc[i].y);
            acc[i].z = fmaf(wv, ev.z, acc[i].z);
            acc[i].w = fmaf(wv, ev.w, acc[i].w);
        }
    }
    const float kf = -logf(10000.0f) / (float)D;
    const int d0 = dq * 4;
    const float f0 = __expf(kf * (float)(d0));
    const float f2 = __expf(kf * (float)(d0 + 2));
    float* outb = out + (size_t)b * T * D + (size_t)t0 * D + d0;
    #pragma unroll
    for (int i = 0; i < 8; ++i) {
        const int tl = tg * 8 + i;
        const float inv = s_winv[tl];
        const float tt = (float)(t0 + tl);
        const float a0 = tt * f0, a2 = tt * f2;
        float4 o;
        o.x = acc[i].x * inv + __sinf(a0);
        o.y = acc[i].y * inv + __cosf(a0);
        o.z = acc[i].z * inv + __sinf(a2);
        o.w = acc[i].w * inv + __cosf(a2);
        *(float4*)(outb + (size_t)tl * D) = o;
    }
}

extern "C" void kernel_launch(void* const* d_in, const int* in_sizes, int n_in,
                              void* d_out, int out_size, void* d_ws, size_t ws_size,
                              hipStream_t stream) {
    const float* enc = (const float*)d_in[0];
    const float* dur = (const float*)d_in[1];
    const float* rng = (const float*)d_in[2];
    float* out = (float*)d_out;

    const int S  = S_FIX;
    const int BS = in_sizes[1];
    const int B  = BS / S;
    const int D  = in_sizes[0] / BS;
    const int T  = out_size / (B * D);

    const size_t need = (size_t)B * D * S * sizeof(unsigned short);  // 4 MB

    if (D == D_FIX && (T % BM) == 0 && ws_size >= need) {
        unsigned short* encT = (unsigned short*)d_ws;
        const int nthr = B * (S / 8) * D;
        const int grid = B * (T / BM);   // 2048
        hipLaunchKernelGGL(transpose_enc_bf16, dim3(nthr / 256), dim3(256), 0, stream,
                           enc, encT);
        // --- ablation probes (outputs overwritten by the real kernel below) ---
        hipLaunchKernelGGL(probe_store, dim3(grid), dim3(256), 0, stream, out, T);
        hipLaunchKernelGGL(probe_kloop, dim3(grid), dim3(256), 0, stream,
                           dur, rng, encT, out, T);
        // --- real kernel (R5) ---
        hipLaunchKernelGGL(gauss_up_mfma, dim3(grid), dim3(256), 0, stream,
                           dur, rng, encT, out, T);
    } else {
        const int ntiles = T / FBM;
        hipLaunchKernelGGL(gauss_up_f32, dim3(B * ntiles), dim3(BLOCK), 0, stream,
                           enc, dur, rng, out, T, D, ntiles);
    }
}

// Round 8
// 78.063 us; speedup vs baseline: 1.2241x; 1.2241x over previous
//
#include <hip/hip_runtime.h>
#include <hip/hip_bf16.h>
#include <math.h>

// Gaussian upsampling, round 8: de-fused 3-stage pipeline (ws = 256 MiB confirmed).
//   K0 transpose_enc_bf16 : enc (B,S,D) f32 -> encT (B,D,S) bf16      (validated)
//   K0b pe_table          : pe[T,D] f32                                (validated)
//   K2 gauss_w            : w (B,T,S) bf16 (exp computed ONCE) + w2inv (B,T) f32
//                           LDS tile -> coalesced copy-out with fused row-sum
//   K3 gauss_gemm         : pure bf16 MFMA GEMM from global (A=wT, B=encT),
//                           zero barriers, per-wave epilogue w2inv*+PE+stores

typedef short  bf16x8 __attribute__((ext_vector_type(8)));
typedef float  f32x4  __attribute__((ext_vector_type(4)));
typedef unsigned short u16x8 __attribute__((ext_vector_type(8)));

#define S_FIX 256
#define D_FIX 256
#define BM 32          // t-rows per tile
#define STG 68         // epilogue staging stride (floats)

static __device__ __forceinline__ unsigned short f2bf(float f) {
    union { float f; unsigned u; } v; v.f = f;
    unsigned r = v.u + 0x7FFFu + ((v.u >> 16) & 1u);   // RNE
    return (unsigned short)(r >> 16);
}

static __device__ __forceinline__ unsigned pack_bf2(float lo, float hi) {
    float2 v; v.x = lo; v.y = hi;
    union { __hip_bfloat162 h; unsigned u; } c;
    c.h = __float22bfloat162_rn(v);
    return c.u;   // low16 = bf16(lo), high16 = bf16(hi)
}

// ---------------- K0: enc (B,S,D) f32 -> encT (B,D,S) bf16 ----------------
__global__ __launch_bounds__(256) void transpose_enc_bf16(
    const float* __restrict__ enc, unsigned short* __restrict__ encT)
{
    const int g  = blockIdx.x * 256 + threadIdx.x;
    const int d  = g & 255;
    const int sc = (g >> 8) & 31;
    const int b  = g >> 13;
    const int s0 = sc * 8;
    const float* p = enc + ((size_t)b << 16) + (size_t)s0 * D_FIX + d;
    u16x8 v;
    #pragma unroll
    for (int j = 0; j < 8; ++j) v[j] = f2bf(p[(size_t)j * D_FIX]);
    *(u16x8*)(encT + ((size_t)b << 16) + (size_t)d * S_FIX + s0) = v;
}

// ---------------- K0b: pe[T,D] table ----------------
__global__ __launch_bounds__(256) void pe_table(float* __restrict__ pe)
{
    const int idx = blockIdx.x * 256 + threadIdx.x;   // T*64 threads
    const int q   = idx & 63;
    const int t   = idx >> 6;
    const float kf = -logf(10000.0f) / (float)D_FIX;
    const float f0 = __expf(kf * (float)(4 * q));
    const float f2 = __expf(kf * (float)(4 * q + 2));
    float s0, c0, s2, c2;
    __sincosf((float)t * f0, &s0, &c0);
    __sincosf((float)t * f2, &s2, &c2);
    f32x4 v; v[0] = s0; v[1] = c0; v[2] = s2; v[3] = c2;
    *(f32x4*)(pe + (size_t)t * D_FIX + 4 * q) = v;
}

// ---------------- K2: w (B,T,S) bf16 + w2inv (B,T) ----------------
__global__ __launch_bounds__(256) void gauss_w(
    const float* __restrict__ dur, const float* __restrict__ rng,
    unsigned short* __restrict__ wT, float* __restrict__ w2inv, int T)
{
    __shared__ float s_c[S_FIX];
    __shared__ float s_nir[S_FIX];
    __shared__ __align__(16) short s_w[BM * S_FIX];   // 16 KB, linear [row][s]

    const int tid  = threadIdx.x;
    const int lane = tid & 63;
    const int ntiles = T / BM;
    const int b  = blockIdx.x / ntiles;
    const int t0 = (blockIdx.x % ntiles) * BM;

    // per-wave scan (all 4 waves redundant; identical-value race is benign)
    {
        f32x4 dv = *(const f32x4*)(dur + b * S_FIX + 4 * lane);
        f32x4 rg = *(const f32x4*)(rng + b * S_FIX + 4 * lane);
        float q0 = dv[0];
        float q1 = q0 + dv[1];
        float q2 = q1 + dv[2];
        float q3 = q2 + dv[3];
        float tot = q3;
        #pragma unroll
        for (int off = 1; off < 64; off <<= 1) {
            float n = __shfl_up(tot, off, 64);
            if (lane >= off) tot += n;
        }
        float excl = __shfl_up(tot, 1, 64);
        if (lane == 0) excl = 0.0f;
        f32x4 c4, n4;
        c4[0] = excl + q0 - 0.5f * dv[0];
        c4[1] = excl + q1 - 0.5f * dv[1];
        c4[2] = excl + q2 - 0.5f * dv[2];
        c4[3] = excl + q3 - 0.5f * dv[3];
        #pragma unroll
        for (int i = 0; i < 4; ++i) n4[i] = -1.0f / (rg[i] * rg[i]);
        *(f32x4*)(s_c   + 4 * lane) = c4;
        *(f32x4*)(s_nir + 4 * lane) = n4;
    }
    asm volatile("s_waitcnt lgkmcnt(0)" ::: "memory");

    // exp phase: thread = (s-pair s2, t-half th); 32 exps/thread, ONE copy total
    {
        const int s2 = tid & 127;
        const int th = tid >> 7;
        float2 cc = *(const float2*)(s_c   + 2 * s2);
        float2 nn = *(const float2*)(s_nir + 2 * s2);
        char* base = (char*)s_w + 4 * s2;
        #pragma unroll
        for (int r = 0; r < 16; ++r) {
            const int row = th * 16 + r;
            const float tt = (float)(t0 + row);
            float e0 = tt - cc.x, e1 = tt - cc.y;
            unsigned p = pack_bf2(__expf(nn.x * e0 * e0), __expf(nn.y * e1 * e1));
            *(unsigned*)(base + row * 512) = p;   // linear; lanes contiguous
        }
    }
    __syncthreads();

    // copy-out (b128 reads, coalesced u16x8 stores) with fused row-sum reduce
    const int hl = tid & 31;   // lane within half-wave; half-wave owns one row
    #pragma unroll
    for (int p = 0; p < 4; ++p) {
        const int row = (tid >> 5) + p * 8;
        u16x8 ch = *(const u16x8*)((const char*)s_w + row * 512 + 16 * hl);
        float s = 0.0f;
        #pragma unroll
        for (int j = 0; j < 8; ++j) s += __uint_as_float((unsigned)ch[j] << 16);
        #pragma unroll
        for (int off = 1; off < 32; off <<= 1) s += __shfl_xor(s, off, 64);
        *(u16x8*)(wT + ((size_t)(b * T + t0 + row) << 8) + 8 * hl) = ch;
        if (hl == 0) w2inv[b * T + t0 + row] = 1.0f / (s + 1e-20f);
    }
}

// ---------------- K3: pure GEMM + epilogue ----------------
__global__ __launch_bounds__(256) void gauss_gemm(
    const unsigned short* __restrict__ wT,    // (B,T,S) bf16
    const unsigned short* __restrict__ encT,  // (B,D,S) bf16
    const float* __restrict__ w2inv,          // (B,T)
    const float* __restrict__ pe,             // (T,D)
    float* __restrict__ out, int T)
{
    __shared__ __align__(16) float s_stg[4][16 * STG];

    const int tid  = threadIdx.x;
    const int lane = tid & 63;
    const int wid  = tid >> 6;
    const int l15  = lane & 15;
    const int lg   = lane >> 4;
    const int ntiles = T / BM;
    const int b  = blockIdx.x / ntiles;
    const int t0 = (blockIdx.x % ntiles) * BM;
    const int d0 = wid * 64;

    // lane l holds w2inv for t-row (l&31)
    const float wv = w2inv[b * T + t0 + (lane & 31)];

    const unsigned short* ap =
        wT + ((size_t)(b * T + t0 + l15) << 8) + lg * 8;       // A row t0+l15
    const unsigned short* eb =
        encT + ((size_t)b << 16) + (size_t)(d0 + l15) * S_FIX + lg * 8;

    f32x4 acc[2][4];
    #pragma unroll
    for (int m = 0; m < 2; ++m)
        #pragma unroll
        for (int n = 0; n < 4; ++n) acc[m][n] = (f32x4){0.f, 0.f, 0.f, 0.f};

    bf16x8 a0c = *(const bf16x8*)(ap);
    bf16x8 a1c = *(const bf16x8*)(ap + 16 * S_FIX);
    bf16x8 bc[4];
    #pragma unroll
    for (int n = 0; n < 4; ++n)
        bc[n] = *(const bf16x8*)(eb + (size_t)n * 16 * S_FIX);

    #pragma unroll 2
    for (int k0 = 0; k0 < S_FIX; k0 += 32) {
        const int kn = (k0 + 32 < S_FIX) ? k0 + 32 : 0;
        bf16x8 a0n = *(const bf16x8*)(ap + kn);
        bf16x8 a1n = *(const bf16x8*)(ap + 16 * S_FIX + kn);
        bf16x8 bn[4];
        #pragma unroll
        for (int n = 0; n < 4; ++n)
            bn[n] = *(const bf16x8*)(eb + (size_t)n * 16 * S_FIX + kn);

        #pragma unroll
        for (int n = 0; n < 4; ++n) {
            acc[0][n] = __builtin_amdgcn_mfma_f32_16x16x32_bf16(a0c, bc[n], acc[0][n], 0, 0, 0);
            acc[1][n] = __builtin_amdgcn_mfma_f32_16x16x32_bf16(a1c, bc[n], acc[1][n], 0, 0, 0);
        }
        a0c = a0n; a1c = a1n;
        #pragma unroll
        for (int n = 0; n < 4; ++n) bc[n] = bn[n];
    }

    // epilogue: per-wave LDS transpose + w2inv + PE + coalesced dwordx4 stores
    float* stg = s_stg[wid];
    const float* peb = pe + (size_t)t0 * D_FIX + d0 + 4 * l15;
    float* ob = out + (size_t)b * T * D_FIX + (size_t)t0 * D_FIX + d0 + 4 * l15;

    #pragma unroll
    for (int m = 0; m < 2; ++m) {
        if (m) asm volatile("s_waitcnt lgkmcnt(0)" ::: "memory");  // WAR on stg
        #pragma unroll
        for (int n = 0; n < 4; ++n)
            #pragma unroll
            for (int r = 0; r < 4; ++r)
                stg[(lg * 4 + r) * STG + n * 16 + l15] = acc[m][n][r];
        asm volatile("s_waitcnt lgkmcnt(0)" ::: "memory");
        #pragma unroll
        for (int i = 0; i < 4; ++i) {
            const int rr = 4 * i + lg;                 // row-local 0..15
            const int tl = m * 16 + rr;
            f32x4 v = *(const f32x4*)(stg + rr * STG + 4 * l15);
            const float iv = __shfl(wv, tl, 64);       // lane tl holds w2inv[t0+tl]
            f32x4 p = *(const f32x4*)(peb + (size_t)tl * D_FIX);
            v[0] = v[0] * iv + p[0];
            v[1] = v[1] * iv + p[1];
            v[2] = v[2] * iv + p[2];
            v[3] = v[3] * iv + p[3];
            *(f32x4*)(ob + (size_t)tl * D_FIX) = v;
        }
    }
}

// ---------------- fallback (round-1 f32 kernel) ----------------
#define FBM 32
#define BLOCK 256
__global__ __launch_bounds__(BLOCK) void gauss_up_f32(
    const float* __restrict__ enc, const float* __restrict__ dur,
    const float* __restrict__ rng, float* __restrict__ out,
    int T, int D, int ntiles)
{
    __shared__ float s_w[FBM][S_FIX];
    __shared__ float s_c[S_FIX];
    __shared__ float s_ir2[S_FIX];
    __shared__ float s_scan[S_FIX];
    __shared__ float s_part[8][FBM];
    __shared__ float s_winv[FBM];

    const int tid = threadIdx.x;
    const int b   = blockIdx.x / ntiles;
    const int t0  = (blockIdx.x % ntiles) * FBM;

    float dv = dur[b * S_FIX + tid];
    s_scan[tid] = dv;
    __syncthreads();
    #pragma unroll
    for (int off = 1; off < S_FIX; off <<= 1) {
        float cur = s_scan[tid];
        float add = (tid >= off) ? s_scan[tid - off] : 0.0f;
        __syncthreads();
        s_scan[tid] = cur + add;
        __syncthreads();
    }
    {
        float e = s_scan[tid];
        float c = e - 0.5f * dv;
        float r = rng[b * S_FIX + tid];
        s_c[tid] = c; s_ir2[tid] = 1.0f / (r * r);
    }
    __syncthreads();
    {
        float cc = s_c[tid], ir = s_ir2[tid];
        #pragma unroll 4
        for (int tl = 0; tl < FBM; ++tl) {
            float tt = (float)(t0 + tl);
            float df = tt - cc;
            s_w[tl][tid] = __expf(-ir * df * df);
        }
    }
    __syncthreads();
    {
        const int t = tid & 31, ch = tid >> 5;
        float ps = 0.0f;
        #pragma unroll 8
        for (int j = 0; j < 32; ++j) ps += s_w[t][ch * 32 + ((j + t) & 31)];
        s_part[ch][t] = ps;
    }
    __syncthreads();
    if (tid < FBM) {
        float w2 = s_part[0][tid] + s_part[1][tid] + s_part[2][tid] + s_part[3][tid]
                 + s_part[4][tid] + s_part[5][tid] + s_part[6][tid] + s_part[7][tid] + 1e-20f;
        s_winv[tid] = 1.0f / w2;
    }
    __syncthreads();

    const int dq = tid & 63, tg = tid >> 6;
    float4 acc[8];
    #pragma unroll
    for (int i = 0; i < 8; ++i) acc[i] = make_float4(0.f, 0.f, 0.f, 0.f);
    const float* encb = enc + (size_t)b * S_FIX * D + (size_t)dq * 4;
    #pragma unroll 4
    for (int s = 0; s < S_FIX; ++s) {
        float4 ev = *(const float4*)(encb + (size_t)s * D);
        #pragma unroll
        for (int i = 0; i < 8; ++i) {
            float wv = s_w[tg * 8 + i][s];
            acc[i].x = fmaf(wv, ev.x, acc[i].x);
            acc[i].y = fmaf(wv, ev.y, acc[i].y);
            acc[i].z = fmaf(wv, ev.z, acc[i].z);
            acc[i].w = fmaf(wv, ev.w, acc[i].w);
        }
    }
    const float kf = -logf(10000.0f) / (float)D;
    const int d0 = dq * 4;
    const float f0 = __expf(kf * (float)(d0));
    const float f2 = __expf(kf * (float)(d0 + 2));
    float* outb = out + (size_t)b * T * D + (size_t)t0 * D + d0;
    #pragma unroll
    for (int i = 0; i < 8; ++i) {
        const int tl = tg * 8 + i;
        const float inv = s_winv[tl];
        const float tt = (float)(t0 + tl);
        const float a0 = tt * f0, a2 = tt * f2;
        float4 o;
        o.x = acc[i].x * inv + __sinf(a0);
        o.y = acc[i].y * inv + __cosf(a0);
        o.z = acc[i].z * inv + __sinf(a2);
        o.w = acc[i].w * inv + __cosf(a2);
        *(float4*)(outb + (size_t)tl * D) = o;
    }
}

extern "C" void kernel_launch(void* const* d_in, const int* in_sizes, int n_in,
                              void* d_out, int out_size, void* d_ws, size_t ws_size,
                              hipStream_t stream) {
    const float* enc = (const float*)d_in[0];
    const float* dur = (const float*)d_in[1];
    const float* rng = (const float*)d_in[2];
    float* out = (float*)d_out;

    const int S  = S_FIX;
    const int BS = in_sizes[1];
    const int B  = BS / S;
    const int D  = in_sizes[0] / BS;
    const int T  = out_size / (B * D);

    const size_t off_encT  = 0;
    const size_t sz_encT   = (size_t)B * D * S * sizeof(unsigned short);  // 4 MB
    const size_t off_pe    = off_encT + sz_encT;
    const size_t sz_pe     = (size_t)T * D * sizeof(float);               // 2 MB
    const size_t off_wT    = off_pe + sz_pe;
    const size_t sz_wT     = (size_t)B * T * S * sizeof(unsigned short);  // 32 MB
    const size_t off_w2    = off_wT + sz_wT;
    const size_t sz_w2     = (size_t)B * T * sizeof(float);               // 256 KB
    const size_t need      = off_w2 + sz_w2;                              // ~38.3 MB

    if (D == D_FIX && S == S_FIX && (T % BM) == 0 && ws_size >= need) {
        unsigned short* encT = (unsigned short*)((char*)d_ws + off_encT);
        float*          pe   = (float*)((char*)d_ws + off_pe);
        unsigned short* wT   = (unsigned short*)((char*)d_ws + off_wT);
        float*          w2   = (float*)((char*)d_ws + off_w2);

        const int grid = B * (T / BM);   // 2048
        hipLaunchKernelGGL(transpose_enc_bf16, dim3(B * (S / 8) * D / 256), dim3(256),
                           0, stream, enc, encT);
        hipLaunchKernelGGL(pe_table, dim3(T * 64 / 256), dim3(256), 0, stream, pe);
        hipLaunchKernelGGL(gauss_w, dim3(grid), dim3(256), 0, stream,
                           dur, rng, wT, w2, T);
        hipLaunchKernelGGL(gauss_gemm, dim3(grid), dim3(256), 0, stream,
                           wT, encT, w2, pe, out, T);
    } else {
        const int ntiles = T / FBM;
        hipLaunchKernelGGL(gauss_up_f32, dim3(B * ntiles), dim3(BLOCK), 0, stream,
                           enc, dur, rng, out, T, D, ntiles);
    }
}

// Round 9
// 67.827 us; speedup vs baseline: 1.4089x; 1.1509x over previous
//
#include <hip/hip_runtime.h>
#include <hip/hip_bf16.h>
#include <math.h>

// Gaussian upsampling, round 9: fat-wave GEMM (128-row superpair per block).
//   K0 transpose_enc_bf16 : enc (B,S,D) f32 -> encT (B,D,S) bf16      (validated)
//   K0b pe_table          : pe[T,D] f32                                (validated)
//   K2 gauss_w            : w (B,T,S) bf16 + w2inv (B,T) f32           (validated)
//   K3b gauss_gemm2       : grid 512, block = (b, 128 t-rows); per 64-row subtile:
//                           acc[4][4], 16 MFMA + 8 prefetched loads per k-step,
//                           per-wave epilogue w2inv*+PE+coalesced stores

typedef short  bf16x8 __attribute__((ext_vector_type(8)));
typedef float  f32x4  __attribute__((ext_vector_type(4)));
typedef unsigned short u16x8 __attribute__((ext_vector_type(8)));

#define S_FIX 256
#define D_FIX 256
#define BM 32          // t-rows per K2 tile
#define STG 68         // epilogue staging stride (floats)

static __device__ __forceinline__ unsigned short f2bf(float f) {
    union { float f; unsigned u; } v; v.f = f;
    unsigned r = v.u + 0x7FFFu + ((v.u >> 16) & 1u);   // RNE
    return (unsigned short)(r >> 16);
}

static __device__ __forceinline__ unsigned pack_bf2(float lo, float hi) {
    float2 v; v.x = lo; v.y = hi;
    union { __hip_bfloat162 h; unsigned u; } c;
    c.h = __float22bfloat162_rn(v);
    return c.u;   // low16 = bf16(lo), high16 = bf16(hi)
}

// ---------------- K0: enc (B,S,D) f32 -> encT (B,D,S) bf16 ----------------
__global__ __launch_bounds__(256) void transpose_enc_bf16(
    const float* __restrict__ enc, unsigned short* __restrict__ encT)
{
    const int g  = blockIdx.x * 256 + threadIdx.x;
    const int d  = g & 255;
    const int sc = (g >> 8) & 31;
    const int b  = g >> 13;
    const int s0 = sc * 8;
    const float* p = enc + ((size_t)b << 16) + (size_t)s0 * D_FIX + d;
    u16x8 v;
    #pragma unroll
    for (int j = 0; j < 8; ++j) v[j] = f2bf(p[(size_t)j * D_FIX]);
    *(u16x8*)(encT + ((size_t)b << 16) + (size_t)d * S_FIX + s0) = v;
}

// ---------------- K0b: pe[T,D] table ----------------
__global__ __launch_bounds__(256) void pe_table(float* __restrict__ pe)
{
    const int idx = blockIdx.x * 256 + threadIdx.x;   // T*64 threads
    const int q   = idx & 63;
    const int t   = idx >> 6;
    const float kf = -logf(10000.0f) / (float)D_FIX;
    const float f0 = __expf(kf * (float)(4 * q));
    const float f2 = __expf(kf * (float)(4 * q + 2));
    float s0, c0, s2, c2;
    __sincosf((float)t * f0, &s0, &c0);
    __sincosf((float)t * f2, &s2, &c2);
    f32x4 v; v[0] = s0; v[1] = c0; v[2] = s2; v[3] = c2;
    *(f32x4*)(pe + (size_t)t * D_FIX + 4 * q) = v;
}

// ---------------- K2: w (B,T,S) bf16 + w2inv (B,T) ----------------
__global__ __launch_bounds__(256) void gauss_w(
    const float* __restrict__ dur, const float* __restrict__ rng,
    unsigned short* __restrict__ wT, float* __restrict__ w2inv, int T)
{
    __shared__ float s_c[S_FIX];
    __shared__ float s_nir[S_FIX];
    __shared__ __align__(16) short s_w[BM * S_FIX];   // 16 KB, linear [row][s]

    const int tid  = threadIdx.x;
    const int lane = tid & 63;
    const int ntiles = T / BM;
    const int b  = blockIdx.x / ntiles;
    const int t0 = (blockIdx.x % ntiles) * BM;

    // per-wave scan (all 4 waves redundant; identical-value race is benign)
    {
        f32x4 dv = *(const f32x4*)(dur + b * S_FIX + 4 * lane);
        f32x4 rg = *(const f32x4*)(rng + b * S_FIX + 4 * lane);
        float q0 = dv[0];
        float q1 = q0 + dv[1];
        float q2 = q1 + dv[2];
        float q3 = q2 + dv[3];
        float tot = q3;
        #pragma unroll
        for (int off = 1; off < 64; off <<= 1) {
            float n = __shfl_up(tot, off, 64);
            if (lane >= off) tot += n;
        }
        float excl = __shfl_up(tot, 1, 64);
        if (lane == 0) excl = 0.0f;
        f32x4 c4, n4;
        c4[0] = excl + q0 - 0.5f * dv[0];
        c4[1] = excl + q1 - 0.5f * dv[1];
        c4[2] = excl + q2 - 0.5f * dv[2];
        c4[3] = excl + q3 - 0.5f * dv[3];
        #pragma unroll
        for (int i = 0; i < 4; ++i) n4[i] = -1.0f / (rg[i] * rg[i]);
        *(f32x4*)(s_c   + 4 * lane) = c4;
        *(f32x4*)(s_nir + 4 * lane) = n4;
    }
    asm volatile("s_waitcnt lgkmcnt(0)" ::: "memory");

    // exp phase: thread = (s-pair s2, t-half th); 32 exps/thread, computed ONCE
    {
        const int s2 = tid & 127;
        const int th = tid >> 7;
        float2 cc = *(const float2*)(s_c   + 2 * s2);
        float2 nn = *(const float2*)(s_nir + 2 * s2);
        char* base = (char*)s_w + 4 * s2;
        #pragma unroll
        for (int r = 0; r < 16; ++r) {
            const int row = th * 16 + r;
            const float tt = (float)(t0 + row);
            float e0 = tt - cc.x, e1 = tt - cc.y;
            unsigned p = pack_bf2(__expf(nn.x * e0 * e0), __expf(nn.y * e1 * e1));
            *(unsigned*)(base + row * 512) = p;
        }
    }
    __syncthreads();

    // copy-out (b128 reads, coalesced u16x8 stores) with fused row-sum reduce
    const int hl = tid & 31;
    #pragma unroll
    for (int p = 0; p < 4; ++p) {
        const int row = (tid >> 5) + p * 8;
        u16x8 ch = *(const u16x8*)((const char*)s_w + row * 512 + 16 * hl);
        float s = 0.0f;
        #pragma unroll
        for (int j = 0; j < 8; ++j) s += __uint_as_float((unsigned)ch[j] << 16);
        #pragma unroll
        for (int off = 1; off < 32; off <<= 1) s += __shfl_xor(s, off, 64);
        *(u16x8*)(wT + ((size_t)(b * T + t0 + row) << 8) + 8 * hl) = ch;
        if (hl == 0) w2inv[b * T + t0 + row] = 1.0f / (s + 1e-20f);
    }
}

// ---------------- K3b: fat-wave GEMM ----------------
__global__ __launch_bounds__(256) void gauss_gemm2(
    const unsigned short* __restrict__ wT,    // (B,T,S) bf16
    const unsigned short* __restrict__ encT,  // (B,D,S) bf16
    const float* __restrict__ w2inv,          // (B,T)
    const float* __restrict__ pe,             // (T,D)
    float* __restrict__ out, int T)
{
    __shared__ __align__(16) float s_stg[4][16 * STG];

    const int tid  = threadIdx.x;
    const int lane = tid & 63;
    const int wid  = tid >> 6;
    const int l15  = lane & 15;
    const int lg   = lane >> 4;
    const int nsup = T / 128;                 // superpairs per batch
    const int b  = blockIdx.x / nsup;
    const int p0 = (blockIdx.x % nsup) * 128; // first t-row of the pair
    const int d0 = wid * 64;

    const unsigned short* eb =
        encT + ((size_t)b << 16) + (size_t)(d0 + l15) * S_FIX + lg * 8;
    float* stg = s_stg[wid];

    #pragma unroll 2
    for (int sub = 0; sub < 2; ++sub) {
        const int t0 = p0 + sub * 64;
        const unsigned short* ap =
            wT + ((size_t)(b * T + t0 + l15) << 8) + lg * 8;   // A row t0+l15
        const float wv0 = w2inv[b * T + t0 + (lane & 31)];       // rows 0..31
        const float wv1 = w2inv[b * T + t0 + 32 + (lane & 31)];  // rows 32..63

        f32x4 acc[4][4];
        #pragma unroll
        for (int m = 0; m < 4; ++m)
            #pragma unroll
            for (int n = 0; n < 4; ++n) acc[m][n] = (f32x4){0.f, 0.f, 0.f, 0.f};

        bf16x8 ac[4], bc[4];
        #pragma unroll
        for (int m = 0; m < 4; ++m)
            ac[m] = *(const bf16x8*)(ap + (size_t)m * 16 * S_FIX);
        #pragma unroll
        for (int n = 0; n < 4; ++n)
            bc[n] = *(const bf16x8*)(eb + (size_t)n * 16 * S_FIX);

        #pragma unroll 2
        for (int k0 = 0; k0 < S_FIX; k0 += 32) {
            const int kn = (k0 + 32 < S_FIX) ? k0 + 32 : 0;   // last: benign reload
            bf16x8 an[4], bn[4];
            #pragma unroll
            for (int m = 0; m < 4; ++m)
                an[m] = *(const bf16x8*)(ap + (size_t)m * 16 * S_FIX + kn);
            #pragma unroll
            for (int n = 0; n < 4; ++n)
                bn[n] = *(const bf16x8*)(eb + (size_t)n * 16 * S_FIX + kn);

            #pragma unroll
            for (int m = 0; m < 4; ++m)
                #pragma unroll
                for (int n = 0; n < 4; ++n)
                    acc[m][n] = __builtin_amdgcn_mfma_f32_16x16x32_bf16(
                        ac[m], bc[n], acc[m][n], 0, 0, 0);

            #pragma unroll
            for (int m = 0; m < 4; ++m) ac[m] = an[m];
            #pragma unroll
            for (int n = 0; n < 4; ++n) bc[n] = bn[n];
        }

        // epilogue: per-wave LDS transpose + w2inv + PE + coalesced stores
        const float* peb = pe + (size_t)t0 * D_FIX + d0 + 4 * l15;
        float* ob = out + (size_t)b * T * D_FIX + (size_t)t0 * D_FIX + d0 + 4 * l15;

        #pragma unroll
        for (int m = 0; m < 4; ++m) {
            asm volatile("s_waitcnt lgkmcnt(0)" ::: "memory");  // WAR on stg
            #pragma unroll
            for (int n = 0; n < 4; ++n)
                #pragma unroll
                for (int r = 0; r < 4; ++r)
                    stg[(lg * 4 + r) * STG + n * 16 + l15] = acc[m][n][r];
            asm volatile("s_waitcnt lgkmcnt(0)" ::: "memory");
            const float wvm = (m < 2) ? wv0 : wv1;
            #pragma unroll
            for (int i = 0; i < 4; ++i) {
                const int rr = 4 * i + lg;                 // row-local 0..15
                const int tl = m * 16 + rr;                // 0..63
                f32x4 v = *(const f32x4*)(stg + rr * STG + 4 * l15);
                const float iv = __shfl(wvm, (m & 1) * 16 + rr, 64);
                f32x4 p = *(const f32x4*)(peb + (size_t)tl * D_FIX);
                v[0] = v[0] * iv + p[0];
                v[1] = v[1] * iv + p[1];
                v[2] = v[2] * iv + p[2];
                v[3] = v[3] * iv + p[3];
                *(f32x4*)(ob + (size_t)tl * D_FIX) = v;
            }
        }
    }
}

// ---------------- fallback (round-1 f32 kernel) ----------------
#define FBM 32
#define BLOCK 256
__global__ __launch_bounds__(BLOCK) void gauss_up_f32(
    const float* __restrict__ enc, const float* __restrict__ dur,
    const float* __restrict__ rng, float* __restrict__ out,
    int T, int D, int ntiles)
{
    __shared__ float s_w[FBM][S_FIX];
    __shared__ float s_c[S_FIX];
    __shared__ float s_ir2[S_FIX];
    __shared__ float s_scan[S_FIX];
    __shared__ float s_part[8][FBM];
    __shared__ float s_winv[FBM];

    const int tid = threadIdx.x;
    const int b   = blockIdx.x / ntiles;
    const int t0  = (blockIdx.x % ntiles) * FBM;

    float dv = dur[b * S_FIX + tid];
    s_scan[tid] = dv;
    __syncthreads();
    #pragma unroll
    for (int off = 1; off < S_FIX; off <<= 1) {
        float cur = s_scan[tid];
        float add = (tid >= off) ? s_scan[tid - off] : 0.0f;
        __syncthreads();
        s_scan[tid] = cur + add;
        __syncthreads();
    }
    {
        float e = s_scan[tid];
        float c = e - 0.5f * dv;
        float r = rng[b * S_FIX + tid];
        s_c[tid] = c; s_ir2[tid] = 1.0f / (r * r);
    }
    __syncthreads();
    {
        float cc = s_c[tid], ir = s_ir2[tid];
        #pragma unroll 4
        for (int tl = 0; tl < FBM; ++tl) {
            float tt = (float)(t0 + tl);
            float df = tt - cc;
            s_w[tl][tid] = __expf(-ir * df * df);
        }
    }
    __syncthreads();
    {
        const int t = tid & 31, ch = tid >> 5;
        float ps = 0.0f;
        #pragma unroll 8
        for (int j = 0; j < 32; ++j) ps += s_w[t][ch * 32 + ((j + t) & 31)];
        s_part[ch][t] = ps;
    }
    __syncthreads();
    if (tid < FBM) {
        float w2 = s_part[0][tid] + s_part[1][tid] + s_part[2][tid] + s_part[3][tid]
                 + s_part[4][tid] + s_part[5][tid] + s_part[6][tid] + s_part[7][tid] + 1e-20f;
        s_winv[tid] = 1.0f / w2;
    }
    __syncthreads();

    const int dq = tid & 63, tg = tid >> 6;
    float4 acc[8];
    #pragma unroll
    for (int i = 0; i < 8; ++i) acc[i] = make_float4(0.f, 0.f, 0.f, 0.f);
    const float* encb = enc + (size_t)b * S_FIX * D + (size_t)dq * 4;
    #pragma unroll 4
    for (int s = 0; s < S_FIX; ++s) {
        float4 ev = *(const float4*)(encb + (size_t)s * D);
        #pragma unroll
        for (int i = 0; i < 8; ++i) {
            float wv = s_w[tg * 8 + i][s];
            acc[i].x = fmaf(wv, ev.x, acc[i].x);
            acc[i].y = fmaf(wv, ev.y, acc[i].y);
            acc[i].z = fmaf(wv, ev.z, acc[i].z);
            acc[i].w = fmaf(wv, ev.w, acc[i].w);
        }
    }
    const float kf = -logf(10000.0f) / (float)D;
    const int d0 = dq * 4;
    const float f0 = __expf(kf * (float)(d0));
    const float f2 = __expf(kf * (float)(d0 + 2));
    float* outb = out + (size_t)b * T * D + (size_t)t0 * D + d0;
    #pragma unroll
    for (int i = 0; i < 8; ++i) {
        const int tl = tg * 8 + i;
        const float inv = s_winv[tl];
        const float tt = (float)(t0 + tl);
        const float a0 = tt * f0, a2 = tt * f2;
        float4 o;
        o.x = acc[i].x * inv + __sinf(a0);
        o.y = acc[i].y * inv + __cosf(a0);
        o.z = acc[i].z * inv + __sinf(a2);
        o.w = acc[i].w * inv + __cosf(a2);
        *(float4*)(outb + (size_t)tl * D) = o;
    }
}

extern "C" void kernel_launch(void* const* d_in, const int* in_sizes, int n_in,
                              void* d_out, int out_size, void* d_ws, size_t ws_size,
                              hipStream_t stream) {
    const float* enc = (const float*)d_in[0];
    const float* dur = (const float*)d_in[1];
    const float* rng = (const float*)d_in[2];
    float* out = (float*)d_out;

    const int S  = S_FIX;
    const int BS = in_sizes[1];
    const int B  = BS / S;
    const int D  = in_sizes[0] / BS;
    const int T  = out_size / (B * D);

    const size_t off_encT  = 0;
    const size_t sz_encT   = (size_t)B * D * S * sizeof(unsigned short);  // 4 MB
    const size_t off_pe    = off_encT + sz_encT;
    const size_t sz_pe     = (size_t)T * D * sizeof(float);               // 2 MB
    const size_t off_wT    = off_pe + sz_pe;
    const size_t sz_wT     = (size_t)B * T * S * sizeof(unsigned short);  // 32 MB
    const size_t off_w2    = off_wT + sz_wT;
    const size_t sz_w2     = (size_t)B * T * sizeof(float);               // 256 KB
    const size_t need      = off_w2 + sz_w2;                              // ~38.3 MB

    if (D == D_FIX && S == S_FIX && (T % 128) == 0 && ws_size >= need) {
        unsigned short* encT = (unsigned short*)((char*)d_ws + off_encT);
        float*          pe   = (float*)((char*)d_ws + off_pe);
        unsigned short* wT   = (unsigned short*)((char*)d_ws + off_wT);
        float*          w2   = (float*)((char*)d_ws + off_w2);

        hipLaunchKernelGGL(transpose_enc_bf16, dim3(B * (S / 8) * D / 256), dim3(256),
                           0, stream, enc, encT);
        hipLaunchKernelGGL(pe_table, dim3(T * 64 / 256), dim3(256), 0, stream, pe);
        hipLaunchKernelGGL(gauss_w, dim3(B * (T / BM)), dim3(256), 0, stream,
                           dur, rng, wT, w2, T);
        hipLaunchKernelGGL(gauss_gemm2, dim3(B * (T / 128)), dim3(256), 0, stream,
                           wT, encT, w2, pe, out, T);
    } else {
        const int ntiles = T / FBM;
        hipLaunchKernelGGL(gauss_up_f32, dim3(B * ntiles), dim3(BLOCK), 0, stream,
                           enc, dur, rng, out, T, D, ntiles);
    }
}

// Round 10
// 36.859 us; speedup vs baseline: 2.5926x; 1.8402x over previous
//
#include <hip/hip_runtime.h>
#include <hip/hip_bf16.h>
#include <math.h>

// Gaussian upsampling, round 10: all-LDS fragment reads (kill global gathers).
//   K0 transpose_enc_bf16 : enc (B,S,D) f32 -> encT bf16 in PRE-PERMUTED layout
//                           [b][dh][dl:128][512B row, chunk16 ^ ((dl&15)<<4)]
//   K1 gauss_fused        : grid 256 (1/CU), 512 thr (8 waves). Block owns
//                           (b, dh, 512 t-rows = 8 tiles of 64):
//     - stage encT[b][dh] 64KB -> LDS once (deep reg-staged, linear)
//     - per-wave shfl scan -> s_c/s_nir (validated benign race)
//     - per tile: coop exp -> swizzled A-tile 64x256 bf16 + w2 partials
//       bar1 ; winv ; all-LDS k-loop (4 MFMA/step/wave, prefetched) ; bar2 ;
//       per-wave LDS-transpose epilogue + inline sincos PE + f32x4 stores

typedef short  bf16x8 __attribute__((ext_vector_type(8)));
typedef float  f32x4  __attribute__((ext_vector_type(4)));
typedef unsigned short u16x8 __attribute__((ext_vector_type(8)));

#define S_FIX 256
#define D_FIX 256
#define DH    128     // d-half per block
#define BM    64      // t-rows per tile
#define NTILE 8       // tiles per block
#define STG   40      // epilogue staging stride (floats, 160B, 16B-aligned)

static __device__ __forceinline__ unsigned short f2bf(float f) {
    union { float f; unsigned u; } v; v.f = f;
    unsigned r = v.u + 0x7FFFu + ((v.u >> 16) & 1u);   // RNE
    return (unsigned short)(r >> 16);
}

static __device__ __forceinline__ unsigned pack_bf2(float lo, float hi) {
    float2 v; v.x = lo; v.y = hi;
    union { __hip_bfloat162 h; unsigned u; } c;
    c.h = __float22bfloat162_rn(v);
    return c.u;   // low16 = bf16(lo), high16 = bf16(hi)
}

// ---------------- K0: enc -> encT (pre-permuted for linear LDS staging) ----------------
__global__ __launch_bounds__(256) void transpose_enc_bf16(
    const float* __restrict__ enc, unsigned short* __restrict__ encT)
{
    const int g  = blockIdx.x * 256 + threadIdx.x;
    const int d  = g & 255;
    const int sc = (g >> 8) & 31;     // 8-s chunk
    const int b  = g >> 13;
    const int s0 = sc * 8;
    const float* p = enc + ((size_t)b << 16) + (size_t)s0 * D_FIX + d;
    u16x8 v;
    #pragma unroll
    for (int j = 0; j < 8; ++j) v[j] = f2bf(p[(size_t)j * D_FIX]);
    const int dh = d >> 7, dl = d & 127;
    const size_t off = ((size_t)b << 17) + ((size_t)dh << 16)
                     + (size_t)dl * 512 + (unsigned)((16 * sc) ^ ((dl & 15) << 4));
    *(u16x8*)((char*)encT + off) = v;
}

// ---------------- K1: fused main ----------------
__global__ __launch_bounds__(512) void gauss_fused(
    const float* __restrict__ dur,            // (B,S)
    const float* __restrict__ rng,            // (B,S,1)
    const unsigned short* __restrict__ encT,  // permuted (B,2,128,256)
    float* __restrict__ out,                  // (B,T,D)
    int T)
{
    __shared__ __align__(16) short s_B[DH * S_FIX];    // 64 KB
    __shared__ __align__(16) short s_A[BM * S_FIX];    // 32 KB
    __shared__ __align__(16) float s_stg[8][16 * STG]; // 20 KB
    __shared__ float s_c[S_FIX];
    __shared__ float s_nir[S_FIX];
    __shared__ float s_part[8][64];
    __shared__ float s_winv[BM];

    const int tid  = threadIdx.x;
    const int lane = tid & 63;
    const int wid  = tid >> 6;       // 0..7
    const int l15  = lane & 15;
    const int lg   = lane >> 4;
    const int bid  = blockIdx.x;
    const int b    = bid >> 3;
    const int rem  = bid & 7;
    const int dh   = rem >> 2;
    const int tb   = (rem & 3) * (BM * NTILE);   // 512-row segment

    // ---- stage encT[b][dh] 64 KB -> s_B (linear; global is pre-permuted) ----
    {
        const char* gB = (const char*)encT + ((size_t)b << 17) + ((size_t)dh << 16);
        char* lB = (char*)s_B;
        #pragma unroll
        for (int it = 0; it < 8; it += 4) {
            u16x8 v0 = *(const u16x8*)(gB + (size_t)(it + 0) * 8192 + tid * 16);
            u16x8 v1 = *(const u16x8*)(gB + (size_t)(it + 1) * 8192 + tid * 16);
            u16x8 v2 = *(const u16x8*)(gB + (size_t)(it + 2) * 8192 + tid * 16);
            u16x8 v3 = *(const u16x8*)(gB + (size_t)(it + 3) * 8192 + tid * 16);
            *(u16x8*)(lB + (size_t)(it + 0) * 8192 + tid * 16) = v0;
            *(u16x8*)(lB + (size_t)(it + 1) * 8192 + tid * 16) = v1;
            *(u16x8*)(lB + (size_t)(it + 2) * 8192 + tid * 16) = v2;
            *(u16x8*)(lB + (size_t)(it + 3) * 8192 + tid * 16) = v3;
        }
    }

    // ---- per-wave scan (all 8 waves redundant; identical-value race benign) ----
    {
        f32x4 dv = *(const f32x4*)(dur + b * S_FIX + 4 * lane);
        f32x4 rg = *(const f32x4*)(rng + b * S_FIX + 4 * lane);
        float q0 = dv[0];
        float q1 = q0 + dv[1];
        float q2 = q1 + dv[2];
        float q3 = q2 + dv[3];
        float tot = q3;
        #pragma unroll
        for (int off = 1; off < 64; off <<= 1) {
            float n = __shfl_up(tot, off, 64);
            if (lane >= off) tot += n;
        }
        float excl = __shfl_up(tot, 1, 64);
        if (lane == 0) excl = 0.0f;
        f32x4 c4, n4;
        c4[0] = excl + q0 - 0.5f * dv[0];
        c4[1] = excl + q1 - 0.5f * dv[1];
        c4[2] = excl + q2 - 0.5f * dv[2];
        c4[3] = excl + q3 - 0.5f * dv[3];
        #pragma unroll
        for (int i = 0; i < 4; ++i) n4[i] = -1.0f / (rg[i] * rg[i]);
        *(f32x4*)(s_c   + 4 * lane) = c4;
        *(f32x4*)(s_nir + 4 * lane) = n4;
    }
    asm volatile("s_waitcnt lgkmcnt(0)" ::: "memory");   // own writes visible

    // per-thread epilogue constants
    const int wm = wid >> 2;            // m-half (32 rows)
    const int wd = wid & 3;             // d-span (32 cols within dh)
    const int q8 = lane & 7;            // f32x4 quad within 32-d span
    const int dq = dh * DH + wd * 32 + 4 * q8;          // absolute d (multiple of 4)
    const float kf = -logf(10000.0f) / (float)D_FIX;
    const float f0 = __expf(kf * (float)dq);
    const float f2 = __expf(kf * (float)(dq + 2));

    // ---- tile loop ----
    for (int tile = 0; tile < NTILE; ++tile) {
        const int t0 = tb + tile * BM;

        // exp phase: thread = (row r, k-chunk kc of 32)
        {
            const int r  = tid & 63;
            const int kc = tid >> 6;
            const float tt = (float)(t0 + r);
            const int swz = (r & 15) << 4;
            char* arow = (char*)s_A + r * 512;
            float ps = 0.0f;
            #pragma unroll
            for (int j2 = 0; j2 < 16; ++j2) {
                const int k = kc * 32 + 2 * j2;
                float2 cc = *(const float2*)(s_c + k);
                float2 nn = *(const float2*)(s_nir + k);
                float e0 = tt - cc.x, e1 = tt - cc.y;
                unsigned p = pack_bf2(__expf(nn.x * e0 * e0), __expf(nn.y * e1 * e1));
                *(unsigned*)(arow + ((2 * k) ^ swz)) = p;
                ps += __uint_as_float(p << 16) + __uint_as_float(p & 0xFFFF0000u);
            }
            s_part[kc][r] = ps;
        }
        __syncthreads();   // bar1: A-tile + partials ready (also covers staging, tile 0)

        if (tid < BM) {
            float w2 = 1e-20f;
            #pragma unroll
            for (int kc = 0; kc < 8; ++kc) w2 += s_part[kc][tid];
            s_winv[tid] = 1.0f / w2;
        }

        // k-loop: all operands from LDS, prefetch next step
        f32x4 acc[2][2];
        #pragma unroll
        for (int m = 0; m < 2; ++m)
            #pragma unroll
            for (int n = 0; n < 2; ++n) acc[m][n] = (f32x4){0.f, 0.f, 0.f, 0.f};

        const char* aB0 = (const char*)s_A + (size_t)(wm * 32 + l15) * 512;
        const char* aB1 = aB0 + 16 * 512;
        const char* bB0 = (const char*)s_B + (size_t)(wd * 32 + l15) * 512;
        const char* bB1 = bB0 + 16 * 512;

        int koff = (2 * (lg * 8)) ^ (l15 << 4);
        bf16x8 a0c = *(const bf16x8*)(aB0 + koff);
        bf16x8 a1c = *(const bf16x8*)(aB1 + koff);
        bf16x8 b0c = *(const bf16x8*)(bB0 + koff);
        bf16x8 b1c = *(const bf16x8*)(bB1 + koff);

        #pragma unroll
        for (int k0 = 0; k0 < S_FIX; k0 += 32) {
            const int kn = (k0 + 32 < S_FIX) ? k0 + 32 : 0;
            const int koffn = (2 * (kn + lg * 8)) ^ (l15 << 4);
            bf16x8 a0n = *(const bf16x8*)(aB0 + koffn);
            bf16x8 a1n = *(const bf16x8*)(aB1 + koffn);
            bf16x8 b0n = *(const bf16x8*)(bB0 + koffn);
            bf16x8 b1n = *(const bf16x8*)(bB1 + koffn);

            acc[0][0] = __builtin_amdgcn_mfma_f32_16x16x32_bf16(a0c, b0c, acc[0][0], 0, 0, 0);
            acc[0][1] = __builtin_amdgcn_mfma_f32_16x16x32_bf16(a0c, b1c, acc[0][1], 0, 0, 0);
            acc[1][0] = __builtin_amdgcn_mfma_f32_16x16x32_bf16(a1c, b0c, acc[1][0], 0, 0, 0);
            acc[1][1] = __builtin_amdgcn_mfma_f32_16x16x32_bf16(a1c, b1c, acc[1][1], 0, 0, 0);

            a0c = a0n; a1c = a1n; b0c = b0n; b1c = b1n;
        }
        __syncthreads();   // bar2: A reads done; winv published

        // epilogue: per-wave staging (wave-local fences), PE inline, f32x4 stores
        float* stg = s_stg[wid];
        #pragma unroll
        for (int mi = 0; mi < 2; ++mi) {
            asm volatile("s_waitcnt lgkmcnt(0)" ::: "memory");  // WAR on stg
            #pragma unroll
            for (int ni = 0; ni < 2; ++ni)
                #pragma unroll
                for (int r = 0; r < 4; ++r)
                    stg[(lg * 4 + r) * STG + ni * 16 + l15] = acc[mi][ni][r];
            asm volatile("s_waitcnt lgkmcnt(0)" ::: "memory");
            const int rl = lane >> 3;        // 0..7
            #pragma unroll
            for (int h = 0; h < 2; ++h) {
                const int rr = rl + 8 * h;                    // 0..15
                const int tr = wm * 32 + mi * 16 + rr;        // row in tile
                f32x4 v = *(const f32x4*)(stg + rr * STG + 4 * q8);
                const float iv = s_winv[tr];
                const float t  = (float)(t0 + tr);
                float sa, ca, sb, cb;
                __sincosf(t * f0, &sa, &ca);
                __sincosf(t * f2, &sb, &cb);
                v[0] = v[0] * iv + sa;
                v[1] = v[1] * iv + ca;
                v[2] = v[2] * iv + sb;
                v[3] = v[3] * iv + cb;
                *(f32x4*)(out + ((size_t)b * T + t0 + tr) * D_FIX + dq) = v;
            }
        }
    }
}

// ---------------- fallback (round-1 f32 kernel) ----------------
#define FBM 32
#define BLOCK 256
__global__ __launch_bounds__(BLOCK) void gauss_up_f32(
    const float* __restrict__ enc, const float* __restrict__ dur,
    const float* __restrict__ rng, float* __restrict__ out,
    int T, int D, int ntiles)
{
    __shared__ float s_w[FBM][S_FIX];
    __shared__ float s_c[S_FIX];
    __shared__ float s_ir2[S_FIX];
    __shared__ float s_scan[S_FIX];
    __shared__ float s_part[8][FBM];
    __shared__ float s_winv[FBM];

    const int tid = threadIdx.x;
    const int b   = blockIdx.x / ntiles;
    const int t0  = (blockIdx.x % ntiles) * FBM;

    float dv = dur[b * S_FIX + tid];
    s_scan[tid] = dv;
    __syncthreads();
    #pragma unroll
    for (int off = 1; off < S_FIX; off <<= 1) {
        float cur = s_scan[tid];
        float add = (tid >= off) ? s_scan[tid - off] : 0.0f;
        __syncthreads();
        s_scan[tid] = cur + add;
        __syncthreads();
    }
    {
        float e = s_scan[tid];
        float c = e - 0.5f * dv;
        float r = rng[b * S_FIX + tid];
        s_c[tid] = c; s_ir2[tid] = 1.0f / (r * r);
    }
    __syncthreads();
    {
        float cc = s_c[tid], ir = s_ir2[tid];
        #pragma unroll 4
        for (int tl = 0; tl < FBM; ++tl) {
            float tt = (float)(t0 + tl);
            float df = tt - cc;
            s_w[tl][tid] = __expf(-ir * df * df);
        }
    }
    __syncthreads();
    {
        const int t = tid & 31, ch = tid >> 5;
        float ps = 0.0f;
        #pragma unroll 8
        for (int j = 0; j < 32; ++j) ps += s_w[t][ch * 32 + ((j + t) & 31)];
        s_part[ch][t] = ps;
    }
    __syncthreads();
    if (tid < FBM) {
        float w2 = s_part[0][tid] + s_part[1][tid] + s_part[2][tid] + s_part[3][tid]
                 + s_part[4][tid] + s_part[5][tid] + s_part[6][tid] + s_part[7][tid] + 1e-20f;
        s_winv[tid] = 1.0f / w2;
    }
    __syncthreads();

    const int dq = tid & 63, tg = tid >> 6;
    float4 acc[8];
    #pragma unroll
    for (int i = 0; i < 8; ++i) acc[i] = make_float4(0.f, 0.f, 0.f, 0.f);
    const float* encb = enc + (size_t)b * S_FIX * D + (size_t)dq * 4;
    #pragma unroll 4
    for (int s = 0; s < S_FIX; ++s) {
        float4 ev = *(const float4*)(encb + (size_t)s * D);
        #pragma unroll
        for (int i = 0; i < 8; ++i) {
            float wv = s_w[tg * 8 + i][s];
            acc[i].x = fmaf(wv, ev.x, acc[i].x);
            acc[i].y = fmaf(wv, ev.y, acc[i].y);
            acc[i].z = fmaf(wv, ev.z, acc[i].z);
            acc[i].w = fmaf(wv, ev.w, acc[i].w);
        }
    }
    const float kf = -logf(10000.0f) / (float)D;
    const int d0 = dq * 4;
    const float f0 = __expf(kf * (float)(d0));
    const float f2 = __expf(kf * (float)(d0 + 2));
    float* outb = out + (size_t)b * T * D + (size_t)t0 * D + d0;
    #pragma unroll
    for (int i = 0; i < 8; ++i) {
        const int tl = tg * 8 + i;
        const float inv = s_winv[tl];
        const float tt = (float)(t0 + tl);
        const float a0 = tt * f0, a2 = tt * f2;
        float4 o;
        o.x = acc[i].x * inv + __sinf(a0);
        o.y = acc[i].y * inv + __cosf(a0);
        o.z = acc[i].z * inv + __sinf(a2);
        o.w = acc[i].w * inv + __cosf(a2);
        *(float4*)(outb + (size_t)tl * D) = o;
    }
}

extern "C" void kernel_launch(void* const* d_in, const int* in_sizes, int n_in,
                              void* d_out, int out_size, void* d_ws, size_t ws_size,
                              hipStream_t stream) {
    const float* enc = (const float*)d_in[0];
    const float* dur = (const float*)d_in[1];
    const float* rng = (const float*)d_in[2];
    float* out = (float*)d_out;

    const int S  = S_FIX;
    const int BS = in_sizes[1];
    const int B  = BS / S;
    const int D  = in_sizes[0] / BS;
    const int T  = out_size / (B * D);

    const size_t need = (size_t)B * D * S * sizeof(unsigned short);  // 4 MB

    if (D == D_FIX && S == S_FIX && (T % (BM * NTILE)) == 0 && ws_size >= need) {
        unsigned short* encT = (unsigned short*)d_ws;
        hipLaunchKernelGGL(transpose_enc_bf16, dim3(B * (S / 8) * D / 256), dim3(256),
                           0, stream, enc, encT);
        const int grid = B * 2 * (T / (BM * NTILE));   // 32*2*4 = 256
        hipLaunchKernelGGL(gauss_fused, dim3(grid), dim3(512), 0, stream,
                           dur, rng, encT, out, T);
    } else {
        const int ntiles = T / FBM;
        hipLaunchKernelGGL(gauss_up_f32, dim3(B * ntiles), dim3(BLOCK), 0, stream,
                           enc, dur, rng, out, T, D, ntiles);
    }
}